// Round 9
// baseline (130.993 us; speedup 1.0000x reference)
//
#include <hip/hip_runtime.h>
#include <hip/hip_bf16.h>
#include <math.h>

typedef __attribute__((ext_vector_type(8))) short bf16x8;
typedef __attribute__((ext_vector_type(4))) float f32x4;
typedef unsigned short ushort_t;

#define NP 14400     // real patches per video
#define NPK 14592    // padded key cols (228 groups of 64): 192 dummy cols
#define NS 4         // column segments
#define NIT 57       // 64-col tiles per segment (57*64 = 3648 cols)
#define TILEB 12288  // bytes per 64-col tile (64 cols * 96 k * 2B)

__device__ __forceinline__ ushort_t f2bf(float f) {
  unsigned u = __float_as_uint(f);
  u += 0x7FFF + ((u >> 16) & 1);   // RNE
  return (ushort_t)(u >> 16);
}
__device__ __forceinline__ float bf2f(ushort_t b) {
  return __uint_as_float(((unsigned)b) << 16);
}

// Fragment-order layouts (16B chunks laid out so consumer reads are
// base + lane*16 + imm — fully coalesced, conflict-free):
// K: chunk = ((p>>6)*12 + ((p>>4)&3)*3 + (d>>5))*64 + ((d>>3)&3)*16 + (p&15)
// Q: chunk = ((p>>4)*3 + (d>>5))*64 + ((d>>3)&3)*16 + (p&15)
__device__ __forceinline__ size_t kidx(int p, int d) {
  return ((size_t)(((p >> 6) * 12 + ((p >> 4) & 3) * 3 + (d >> 5)) * 64
          + ((d >> 3) & 3) * 16 + (p & 15))) * 8 + (d & 7);
}
__device__ __forceinline__ size_t qidx(int p, int d) {
  return ((size_t)(((p >> 4) * 3 + (d >> 5)) * 64
          + ((d >> 3) & 3) * 16 + (p & 15))) * 8 + (d & 7);
}

// ---------------- prep: patches -> bf16 in fragment order -----------------
// Q: slots 0..74 = bf16(-2*q), 75,76 = 1.0, rest 0; qn = fp32 norm.
// K: slots 0..74 = bf16(k), 75 = bf16(kn), 76 = bf16(kn residual), rest 0.
// K pad cols (p >= NP): zero data, norm slot = 3.39e38 (never wins the min).
// Also inits rminb to ordered-uint +inf and zeroes the done-counter.
__global__ __launch_bounds__(256) void prep_kernel(
    const float* __restrict__ resv, const float* __restrict__ valv,
    ushort_t* __restrict__ Qb, ushort_t* __restrict__ Kb,
    float* __restrict__ qn, unsigned* __restrict__ rminb,
    unsigned* __restrict__ counter) {
  int w = threadIdx.x >> 6;
  int lane = threadIdx.x & 63;
  int pg = blockIdx.x * 4 + w;          // 0..28991
  if (pg == 0 && lane == 0) *counter = 0;
  int isK = pg >= NP;
  int p = isK ? pg - NP : pg;           // Q: 0..14399  K: 0..14591

  if (isK && p >= NP) {                 // dummy key col
    Kb[kidx(p, lane)] = 0;
    if (lane < 32)
      Kb[kidx(p, lane + 64)] = (lane == 11) ? (ushort_t)0x7F7F : (ushort_t)0;
    return;
  }

  const float* src = isK ? valv : resv;
  int t = p / 3600; int rem = p - t * 3600;
  int y = rem / 60;  int x = rem - y * 60;

  float v0, v1 = 0.f;
  {
    int d = lane;  // < 75 always
    int c = d / 25; int r = d - c * 25; int dy = r / 5; int dx = r - dy * 5;
    v0 = src[((c * 4 + t) * 64 + (y + dy)) * 64 + (x + dx)];
  }
  if (lane < 11) {
    int d = lane + 64;
    int c = d / 25; int r = d - c * 25; int dy = r / 5; int dx = r - dy * 5;
    v1 = src[((c * 4 + t) * 64 + (y + dy)) * 64 + (x + dx)];
  }
  ushort_t b0 = f2bf(v0), b1 = f2bf(v1);
  float f0 = bf2f(b0), f1 = bf2f(b1);

  float sq = f0 * f0 + f1 * f1;
  #pragma unroll
  for (int off = 1; off < 64; off <<= 1) sq += __shfl_xor(sq, off, 64);

  if (isK) {
    ushort_t khi = f2bf(sq);
    ushort_t klo = f2bf(sq - bf2f(khi));
    ushort_t s1 = (lane < 11) ? b1
                : (lane == 11 ? khi : (lane == 12 ? klo : (ushort_t)0));
    Kb[kidx(p, lane)] = b0;
    if (lane < 32) Kb[kidx(p, lane + 64)] = s1;
  } else {
    ushort_t s0 = f2bf(-2.f * f0);
    ushort_t s1 = (lane < 11) ? f2bf(-2.f * f1)
                : ((lane == 11 || lane == 12) ? (ushort_t)0x3F80 : (ushort_t)0);
    Qb[qidx(p, lane)] = s0;
    if (lane < 32) Qb[qidx(p, lane + 64)] = s1;
    if (lane == 0) { qn[p] = sq; rminb[p] = 0xFFFFFFFFu; }
  }
}

// ------- main: wave-private 64x16 tiles, B streamed to VGPRs, depth-2 -----
// 900 blocks = exactly one residency round at 4 blocks/CU. Fused last-block
// final reduction (threadfence + counter).
__global__ __launch_bounds__(256, 4) void knn_kernel(
    const ushort_t* __restrict__ Qb, const ushort_t* __restrict__ Kb,
    unsigned* __restrict__ rminb, const float* __restrict__ qn,
    unsigned* __restrict__ counter, float* __restrict__ out) {
  // XCD-bijective swizzle: 900 blocks, q=112 r=4; lin is ns-major so each
  // XCD sees one 0.7MB key segment + consecutive 64-row A blocks.
  int b = blockIdx.x;
  int xcd = b & 7, pos = b >> 3;
  int lin = (xcd < 4 ? xcd * 113 : 452 + (xcd - 4) * 112) + pos;
  int ns = lin / 225, rowblk = lin - ns * 225;
  int brow = rowblk * 64;
  int lane = threadIdx.x & 63;
  int w = threadIdx.x >> 6;
  int l15 = lane & 15, l4 = lane >> 4;

  // B stream base: fragment-order Kb; wave's 16-col slice of each 64-col
  // tile is 3 contiguous 1KB chunks (lane-contiguous 16B each).
  const char* gW = (const char*)Kb + (size_t)(ns * NIT) * TILEB
                   + w * 3072 + lane * 16;

  // A fragments: 64 rows x 96 k, fragment-order Qb, lane-contiguous loads
  const char* Aw = (const char*)Qb + (size_t)(brow >> 4) * 3072 + lane * 16;
  bf16x8 af[4][3];
  #pragma unroll
  for (int rt = 0; rt < 4; ++rt)
    #pragma unroll
    for (int ks = 0; ks < 3; ++ks)
      af[rt][ks] = *(const bf16x8*)(Aw + (rt * 3 + ks) * 1024);

  float rmin[4][4];
  #pragma unroll
  for (int rt = 0; rt < 4; ++rt)
    #pragma unroll
    for (int j = 0; j < 4; ++j) rmin[rt][j] = INFINITY;

  const f32x4 fz = {0.f, 0.f, 0.f, 0.f};

  // depth-2 register rotation; all indices literal at every call site
  bf16x8 bbuf[2][3];

  auto loadB = [&](int bi, int it) {   // bi literal at call sites
    const char* g = gW + (size_t)it * TILEB;
    #pragma unroll
    for (int ks = 0; ks < 3; ++ks)
      bbuf[bi][ks] = *(const bf16x8*)(g + ks * 1024);
  };

  auto compute = [&](int bi) {         // bi literal at call sites
    f32x4 acc[4];
    __builtin_amdgcn_s_setprio(1);
    {
      bf16x8 bv = bbuf[bi][0];
      #pragma unroll
      for (int rt = 0; rt < 4; ++rt)
        acc[rt] = __builtin_amdgcn_mfma_f32_16x16x32_bf16(af[rt][0], bv, fz, 0, 0, 0);
    }
    #pragma unroll
    for (int ks = 1; ks < 3; ++ks) {
      bf16x8 bv = bbuf[bi][ks];
      #pragma unroll
      for (int rt = 0; rt < 4; ++rt)
        acc[rt] = __builtin_amdgcn_mfma_f32_16x16x32_bf16(af[rt][ks], bv, acc[rt], 0, 0, 0);
    }
    __builtin_amdgcn_s_setprio(0);
    #pragma unroll
    for (int rt = 0; rt < 4; ++rt)
      #pragma unroll
      for (int j = 0; j < 4; ++j)
        rmin[rt][j] = fminf(rmin[rt][j], acc[rt][j]);
  };

  loadB(0, 0);
  loadB(1, 1);

  // main loop: compute(b)[k] then immediately re-issue load into buf b for
  // k+2 (WAR-safe: the load follows the consuming MFMAs in program order).
  int k = 0;
  #pragma unroll 1
  for (int tri = 0; tri < 27; ++tri, k += 2) {
    compute(0); loadB(0, k + 2);
    compute(1); loadB(1, k + 3);
  }
  // k == 54; computed 0..53; in flight: (0,54),(1,55)
  compute(0); loadB(0, 56);   // iter 54
  compute(1);                  // iter 55
  compute(0);                  // iter 56

  // min over the 16 key-cols (l15 lanes), then device atomicMin per row
  #pragma unroll
  for (int rt = 0; rt < 4; ++rt)
    #pragma unroll
    for (int j = 0; j < 4; ++j) {
      float m = rmin[rt][j];
      m = fminf(m, __shfl_xor(m, 1, 64));
      m = fminf(m, __shfl_xor(m, 2, 64));
      m = fminf(m, __shfl_xor(m, 4, 64));
      m = fminf(m, __shfl_xor(m, 8, 64));
      if (l15 == 0) {
        unsigned bu = __float_as_uint(m);
        unsigned tu = bu ^ (unsigned)(((int)bu >> 31) | (int)0x80000000);
        atomicMin(&rminb[brow + rt * 16 + l4 * 4 + j], tu);
      }
    }

  // ---- last-block final reduction (deterministic) ----
  __threadfence();
  __shared__ unsigned amLast;
  if (threadIdx.x == 0) amLast = (atomicAdd(counter, 1) == 899u);
  __syncthreads();
  if (!amLast) return;
  __threadfence();

  const volatile unsigned* rv = (const volatile unsigned*)rminb;
  int tid = threadIdx.x;
  float s = 0.f;
  for (int i = tid; i < NP; i += 256) {
    unsigned u = rv[i];
    unsigned bu = (u & 0x80000000u) ? (u ^ 0x80000000u) : ~u;
    s += __uint_as_float(bu) + qn[i];
  }
  #pragma unroll
  for (int off = 32; off; off >>= 1) s += __shfl_down(s, off, 64);
  __shared__ float red[4];
  if ((tid & 63) == 0) red[tid >> 6] = s;
  __syncthreads();
  if (tid == 0) out[0] = red[0] + red[1] + red[2] + red[3];
}

extern "C" void kernel_launch(void* const* d_in, const int* in_sizes, int n_in,
                              void* d_out, int out_size, void* d_ws, size_t ws_size,
                              hipStream_t stream) {
  const float* resv = (const float*)d_in[0];
  const float* valv = (const float*)d_in[1];
  char* ws = (char*)d_ws;
  ushort_t* Qb      = (ushort_t*)ws;                 // 2,764,800 B
  ushort_t* Kb      = (ushort_t*)(ws + 2764800);     // 2,801,664 B (14592 cols)
  float* qn         = (float*)(ws + 5566464);        //    57,600 B
  unsigned* rminb   = (unsigned*)(ws + 5624064);     //    57,600 B
  unsigned* counter = (unsigned*)(ws + 5681664);     //         4 B
  float* out = (float*)d_out;

  prep_kernel<<<7248, 256, 0, stream>>>(resv, valv, Qb, Kb, qn, rminb, counter);
  knn_kernel<<<900, 256, 0, stream>>>(Qb, Kb, rminb, qn, counter, out);
}

// Round 10
// 55.546 us; speedup vs baseline: 2.3583x; 2.3583x over previous
//
#include <hip/hip_runtime.h>
#include <hip/hip_bf16.h>
#include <math.h>

typedef __attribute__((ext_vector_type(8))) short bf16x8;
typedef __attribute__((ext_vector_type(4))) float f32x4;
typedef unsigned short ushort_t;

#define NP 14400     // real patches per video
#define NPK 14592    // padded key cols: 192 dummy cols (norm=3.4e38)
#define NS 4         // column segments
#define NIT 57       // 64-col tiles per segment (57*64 = 3648 cols)
#define TILEB 12288  // bytes per 64-col tile (64 cols * 96 k * 2B)

__device__ __forceinline__ ushort_t f2bf(float f) {
  unsigned u = __float_as_uint(f);
  u += 0x7FFF + ((u >> 16) & 1);   // RNE
  return (ushort_t)(u >> 16);
}
__device__ __forceinline__ float bf2f(ushort_t b) {
  return __uint_as_float(((unsigned)b) << 16);
}

// Fragment-order layouts (16B chunks laid out so consumer reads are
// base + lane*16 + imm — fully coalesced, conflict-free):
// K: chunk = ((p>>6)*12 + ((p>>4)&3)*3 + (d>>5))*64 + ((d>>3)&3)*16 + (p&15)
// Q: chunk = ((p>>4)*3 + (d>>5))*64 + ((d>>3)&3)*16 + (p&15)
__device__ __forceinline__ size_t kidx(int p, int d) {
  return ((size_t)(((p >> 6) * 12 + ((p >> 4) & 3) * 3 + (d >> 5)) * 64
          + ((d >> 3) & 3) * 16 + (p & 15))) * 8 + (d & 7);
}
__device__ __forceinline__ size_t qidx(int p, int d) {
  return ((size_t)(((p >> 4) * 3 + (d >> 5)) * 64
          + ((d >> 3) & 3) * 16 + (p & 15))) * 8 + (d & 7);
}

// ---------------- prep: patches -> bf16 in fragment order -----------------
// Q: slots 0..74 = bf16(-2*q), 75,76 = 1.0, rest 0; qn = fp32 norm.
// K: slots 0..74 = bf16(k), 75 = bf16(kn), 76 = bf16(kn residual), rest 0.
// K pad cols (p >= NP): zero data, norm slot = 3.39e38 (never wins the min).
__global__ __launch_bounds__(256) void prep_kernel(
    const float* __restrict__ resv, const float* __restrict__ valv,
    ushort_t* __restrict__ Qb, ushort_t* __restrict__ Kb,
    float* __restrict__ qn, unsigned* __restrict__ rminb) {
  int w = threadIdx.x >> 6;
  int lane = threadIdx.x & 63;
  int pg = blockIdx.x * 4 + w;          // 0..28991
  int isK = pg >= NP;
  int p = isK ? pg - NP : pg;           // Q: 0..14399  K: 0..14591

  if (isK && p >= NP) {                 // dummy key col
    Kb[kidx(p, lane)] = 0;
    if (lane < 32)
      Kb[kidx(p, lane + 64)] = (lane == 11) ? (ushort_t)0x7F7F : (ushort_t)0;
    return;
  }

  const float* src = isK ? valv : resv;
  int t = p / 3600; int rem = p - t * 3600;
  int y = rem / 60;  int x = rem - y * 60;

  float v0, v1 = 0.f;
  {
    int d = lane;  // < 75 always
    int c = d / 25; int r = d - c * 25; int dy = r / 5; int dx = r - dy * 5;
    v0 = src[((c * 4 + t) * 64 + (y + dy)) * 64 + (x + dx)];
  }
  if (lane < 11) {
    int d = lane + 64;
    int c = d / 25; int r = d - c * 25; int dy = r / 5; int dx = r - dy * 5;
    v1 = src[((c * 4 + t) * 64 + (y + dy)) * 64 + (x + dx)];
  }
  ushort_t b0 = f2bf(v0), b1 = f2bf(v1);
  float f0 = bf2f(b0), f1 = bf2f(b1);

  float sq = f0 * f0 + f1 * f1;
  #pragma unroll
  for (int off = 1; off < 64; off <<= 1) sq += __shfl_xor(sq, off, 64);

  if (isK) {
    ushort_t khi = f2bf(sq);
    ushort_t klo = f2bf(sq - bf2f(khi));
    ushort_t s1 = (lane < 11) ? b1
                : (lane == 11 ? khi : (lane == 12 ? klo : (ushort_t)0));
    Kb[kidx(p, lane)] = b0;
    if (lane < 32) Kb[kidx(p, lane + 64)] = s1;
  } else {
    ushort_t s0 = f2bf(-2.f * f0);
    ushort_t s1 = (lane < 11) ? f2bf(-2.f * f1)
                : ((lane == 11 || lane == 12) ? (ushort_t)0x3F80 : (ushort_t)0);
    Qb[qidx(p, lane)] = s0;
    if (lane < 32) Qb[qidx(p, lane + 64)] = s1;
    if (lane == 0) { qn[p] = sq; rminb[p] = 0xFFFFFFFFu; }
  }
}

// ------- main: wave-private 64x16 tiles, B streamed to VGPRs, depth-2 -----
// 900 blocks = exactly one residency round at 4 blocks/CU.
__global__ __launch_bounds__(256, 4) void knn_kernel(
    const ushort_t* __restrict__ Qb, const ushort_t* __restrict__ Kb,
    unsigned* __restrict__ rminb) {
  // XCD-bijective swizzle: 900 blocks, q=112 r=4; lin is ns-major so each
  // XCD sees one 0.7MB key segment + consecutive 64-row A blocks.
  int b = blockIdx.x;
  int xcd = b & 7, pos = b >> 3;
  int lin = (xcd < 4 ? xcd * 113 : 452 + (xcd - 4) * 112) + pos;
  int ns = lin / 225, rowblk = lin - ns * 225;
  int brow = rowblk * 64;
  int lane = threadIdx.x & 63;
  int w = threadIdx.x >> 6;
  int l15 = lane & 15, l4 = lane >> 4;

  // B stream base: fragment-order Kb; wave's 16-col slice of each 64-col
  // tile is 3 contiguous 1KB chunks (lane-contiguous 16B each).
  const char* gW = (const char*)Kb + (size_t)(ns * NIT) * TILEB
                   + w * 3072 + lane * 16;

  // A fragments: 64 rows x 96 k, fragment-order Qb, lane-contiguous loads
  const char* Aw = (const char*)Qb + (size_t)(brow >> 4) * 3072 + lane * 16;
  bf16x8 af[4][3];
  #pragma unroll
  for (int rt = 0; rt < 4; ++rt)
    #pragma unroll
    for (int ks = 0; ks < 3; ++ks)
      af[rt][ks] = *(const bf16x8*)(Aw + (rt * 3 + ks) * 1024);

  float rmin[4][4];
  #pragma unroll
  for (int rt = 0; rt < 4; ++rt)
    #pragma unroll
    for (int j = 0; j < 4; ++j) rmin[rt][j] = INFINITY;

  const f32x4 fz = {0.f, 0.f, 0.f, 0.f};

  // depth-2 register rotation; all indices literal at every call site
  bf16x8 bbuf[2][3];

  auto loadB = [&](int bi, int it) {   // bi literal at call sites
    const char* g = gW + (size_t)it * TILEB;
    #pragma unroll
    for (int ks = 0; ks < 3; ++ks)
      bbuf[bi][ks] = *(const bf16x8*)(g + ks * 1024);
  };

  auto compute = [&](int bi) {         // bi literal at call sites
    f32x4 acc[4];
    {
      bf16x8 bv = bbuf[bi][0];
      #pragma unroll
      for (int rt = 0; rt < 4; ++rt)
        acc[rt] = __builtin_amdgcn_mfma_f32_16x16x32_bf16(af[rt][0], bv, fz, 0, 0, 0);
    }
    #pragma unroll
    for (int ks = 1; ks < 3; ++ks) {
      bf16x8 bv = bbuf[bi][ks];
      #pragma unroll
      for (int rt = 0; rt < 4; ++rt)
        acc[rt] = __builtin_amdgcn_mfma_f32_16x16x32_bf16(af[rt][ks], bv, acc[rt], 0, 0, 0);
    }
    #pragma unroll
    for (int rt = 0; rt < 4; ++rt)
      #pragma unroll
      for (int j = 0; j < 4; ++j)
        rmin[rt][j] = fminf(rmin[rt][j], acc[rt][j]);
  };

  loadB(0, 0);
  loadB(1, 1);

  // main loop: compute(b)[k] then immediately re-issue load into buf b for
  // k+2 (WAR-safe: the load follows the consuming MFMAs in program order).
  int k = 0;
  #pragma unroll 1
  for (int tri = 0; tri < 27; ++tri, k += 2) {
    compute(0); loadB(0, k + 2);
    compute(1); loadB(1, k + 3);
  }
  // k == 54; computed 0..53; in flight: (0,54),(1,55)
  compute(0); loadB(0, 56);   // iter 54
  compute(1);                  // iter 55
  compute(0);                  // iter 56

  // min over the 16 key-cols (l15 lanes), then device atomicMin per row
  #pragma unroll
  for (int rt = 0; rt < 4; ++rt)
    #pragma unroll
    for (int j = 0; j < 4; ++j) {
      float m = rmin[rt][j];
      m = fminf(m, __shfl_xor(m, 1, 64));
      m = fminf(m, __shfl_xor(m, 2, 64));
      m = fminf(m, __shfl_xor(m, 4, 64));
      m = fminf(m, __shfl_xor(m, 8, 64));
      if (l15 == 0) {
        unsigned bu = __float_as_uint(m);
        unsigned tu = bu ^ (unsigned)(((int)bu >> 31) | (int)0x80000000);
        atomicMin(&rminb[brow + rt * 16 + l4 * 4 + j], tu);
      }
    }
}

// ------ final stage 1: decode + add qn, per-block partial sums ------------
__global__ __launch_bounds__(64) void final1_kernel(
    const unsigned* __restrict__ rminb, const float* __restrict__ qn,
    float* __restrict__ partial) {
  int r = blockIdx.x * 64 + threadIdx.x;   // grid 225 covers 14400
  unsigned u = rminb[r];
  unsigned bu = (u & 0x80000000u) ? (u ^ 0x80000000u) : ~u;
  float val = __uint_as_float(bu) + qn[r];
  #pragma unroll
  for (int off = 32; off; off >>= 1) val += __shfl_down(val, off, 64);
  if (threadIdx.x == 0) partial[blockIdx.x] = val;
}

// ------ final stage 2: deterministic sum of 225 partials ------------------
__global__ __launch_bounds__(256) void final2_kernel(
    const float* __restrict__ partial, float* __restrict__ out) {
  int t = threadIdx.x;
  float v = (t < 225) ? partial[t] : 0.f;
  #pragma unroll
  for (int off = 32; off; off >>= 1) v += __shfl_down(v, off, 64);
  __shared__ float s[4];
  if ((t & 63) == 0) s[t >> 6] = v;
  __syncthreads();
  if (t == 0) out[0] = s[0] + s[1] + s[2] + s[3];
}

extern "C" void kernel_launch(void* const* d_in, const int* in_sizes, int n_in,
                              void* d_out, int out_size, void* d_ws, size_t ws_size,
                              hipStream_t stream) {
  const float* resv = (const float*)d_in[0];
  const float* valv = (const float*)d_in[1];
  char* ws = (char*)d_ws;
  ushort_t* Qb      = (ushort_t*)ws;                 // 2,764,800 B
  ushort_t* Kb      = (ushort_t*)(ws + 2764800);     // 2,801,664 B (14592 cols)
  float* qn         = (float*)(ws + 5566464);        //    57,600 B
  unsigned* rminb   = (unsigned*)(ws + 5624064);     //    57,600 B
  float* partial    = (float*)(ws + 5681664);        //       900 B
  float* out = (float*)d_out;

  prep_kernel<<<7248, 256, 0, stream>>>(resv, valv, Qb, Kb, qn, rminb);
  knn_kernel<<<900, 256, 0, stream>>>(Qb, Kb, rminb);
  final1_kernel<<<225, 64, 0, stream>>>(rminb, qn, partial);
  final2_kernel<<<1, 256, 0, stream>>>(partial, out);
}

// Round 11
// 53.700 us; speedup vs baseline: 2.4393x; 1.0344x over previous
//
#include <hip/hip_runtime.h>
#include <hip/hip_bf16.h>
#include <math.h>

typedef __attribute__((ext_vector_type(8))) short bf16x8;
typedef __attribute__((ext_vector_type(4))) float f32x4;
typedef unsigned short ushort_t;

#define NP 14400     // real patches per video
#define NPK 14592    // padded rows/cols (114 groups of 128; 192 dummies)
#define NS 4         // column segments
#define NIT 57       // 64-col tiles per segment (57*64 = 3648 cols)
#define TILEB 12288  // bytes per 64-col tile (64 cols * 96 k * 2B)

__device__ __forceinline__ ushort_t f2bf(float f) {
  unsigned u = __float_as_uint(f);
  u += 0x7FFF + ((u >> 16) & 1);   // RNE
  return (ushort_t)(u >> 16);
}
__device__ __forceinline__ float bf2f(ushort_t b) {
  return __uint_as_float(((unsigned)b) << 16);
}

// Fragment-order layouts (16B chunks laid out so consumer reads are
// base + lane*16 + imm — fully coalesced, conflict-free):
// K: chunk = ((p>>6)*12 + ((p>>4)&3)*3 + (d>>5))*64 + ((d>>3)&3)*16 + (p&15)
// Q: chunk = ((p>>4)*3 + (d>>5))*64 + ((d>>3)&3)*16 + (p&15)
__device__ __forceinline__ size_t kidx(int p, int d) {
  return ((size_t)(((p >> 6) * 12 + ((p >> 4) & 3) * 3 + (d >> 5)) * 64
          + ((d >> 3) & 3) * 16 + (p & 15))) * 8 + (d & 7);
}
__device__ __forceinline__ size_t qidx(int p, int d) {
  return ((size_t)(((p >> 4) * 3 + (d >> 5)) * 64
          + ((d >> 3) & 3) * 16 + (p & 15))) * 8 + (d & 7);
}

// ---------------- prep: patches -> bf16 in fragment order -----------------
// Q: slots 0..74 = bf16(-2*q), 75,76 = 1.0, rest 0; qn = fp32 norm.
// K: slots 0..74 = bf16(k), 75 = bf16(kn), 76 = bf16(kn residual), rest 0.
// Pad rows/cols (p >= NP): Q pad = all zeros (qn=0); K pad = zero data with
// norm slot 3.39e38 (never wins the min).
__global__ __launch_bounds__(256) void prep_kernel(
    const float* __restrict__ resv, const float* __restrict__ valv,
    ushort_t* __restrict__ Qb, ushort_t* __restrict__ Kb,
    float* __restrict__ qn, unsigned* __restrict__ rminb) {
  int w = threadIdx.x >> 6;
  int lane = threadIdx.x & 63;
  int pg = blockIdx.x * 4 + w;          // 0..29183
  int isK = pg >= NPK;
  int p = isK ? pg - NPK : pg;          // 0..14591

  if (p >= NP) {                        // pad row/col
    if (isK) {
      Kb[kidx(p, lane)] = 0;
      if (lane < 32)
        Kb[kidx(p, lane + 64)] = (lane == 11) ? (ushort_t)0x7F7F : (ushort_t)0;
    } else {
      Qb[qidx(p, lane)] = 0;
      if (lane < 32) Qb[qidx(p, lane + 64)] = 0;
      if (lane == 0) { qn[p] = 0.f; rminb[p] = 0xFFFFFFFFu; }
    }
    return;
  }

  const float* src = isK ? valv : resv;
  int t = p / 3600; int rem = p - t * 3600;
  int y = rem / 60;  int x = rem - y * 60;

  float v0, v1 = 0.f;
  {
    int d = lane;  // < 75 always
    int c = d / 25; int r = d - c * 25; int dy = r / 5; int dx = r - dy * 5;
    v0 = src[((c * 4 + t) * 64 + (y + dy)) * 64 + (x + dx)];
  }
  if (lane < 11) {
    int d = lane + 64;
    int c = d / 25; int r = d - c * 25; int dy = r / 5; int dx = r - dy * 5;
    v1 = src[((c * 4 + t) * 64 + (y + dy)) * 64 + (x + dx)];
  }
  ushort_t b0 = f2bf(v0), b1 = f2bf(v1);
  float f0 = bf2f(b0), f1 = bf2f(b1);

  float sq = f0 * f0 + f1 * f1;
  #pragma unroll
  for (int off = 1; off < 64; off <<= 1) sq += __shfl_xor(sq, off, 64);

  if (isK) {
    ushort_t khi = f2bf(sq);
    ushort_t klo = f2bf(sq - bf2f(khi));
    ushort_t s1 = (lane < 11) ? b1
                : (lane == 11 ? khi : (lane == 12 ? klo : (ushort_t)0));
    Kb[kidx(p, lane)] = b0;
    if (lane < 32) Kb[kidx(p, lane + 64)] = s1;
  } else {
    ushort_t s0 = f2bf(-2.f * f0);
    ushort_t s1 = (lane < 11) ? f2bf(-2.f * f1)
                : ((lane == 11 || lane == 12) ? (ushort_t)0x3F80 : (ushort_t)0);
    Qb[qidx(p, lane)] = s0;
    if (lane < 32) Qb[qidx(p, lane + 64)] = s1;
    if (lane == 0) { qn[p] = sq; rminb[p] = 0xFFFFFFFFu; }
  }
}

// ------- main: wave-private 128x16 tiles, B streamed to VGPRs, depth-2 ----
// 456 blocks (= 8 * 57), 2 blocks/CU resident -> single residency round.
// 24 MFMA per 3KB of B halves the L2 bandwidth needed per MFMA-cycle.
__global__ __launch_bounds__(256, 2) void knn_kernel(
    const ushort_t* __restrict__ Qb, const ushort_t* __restrict__ Kb,
    unsigned* __restrict__ rminb) {
  // XCD-bijective swizzle: 456 = 8*57 exactly; ns-major so 2 XCDs share one
  // 0.7MB key segment (L2-resident) and partition its row blocks.
  int b = blockIdx.x;
  int lin = (b & 7) * 57 + (b >> 3);
  int ns = lin / 114, rowblk = lin - ns * 114;
  int brow = rowblk * 128;
  int lane = threadIdx.x & 63;
  int w = threadIdx.x >> 6;
  int l15 = lane & 15, l4 = lane >> 4;

  // B stream base: fragment-order Kb; wave's 16-col slice of each 64-col
  // tile is 3 contiguous 1KB chunks (lane-contiguous 16B each).
  const char* gW = (const char*)Kb + (size_t)(ns * NIT) * TILEB
                   + w * 3072 + lane * 16;

  // A fragments: 128 rows x 96 k, fragment-order Qb, lane-contiguous loads
  const char* Aw = (const char*)Qb + (size_t)(brow >> 4) * 3072 + lane * 16;
  bf16x8 af[8][3];
  #pragma unroll
  for (int rt = 0; rt < 8; ++rt)
    #pragma unroll
    for (int ks = 0; ks < 3; ++ks)
      af[rt][ks] = *(const bf16x8*)(Aw + (rt * 3 + ks) * 1024);

  float rmin[8][4];
  #pragma unroll
  for (int rt = 0; rt < 8; ++rt)
    #pragma unroll
    for (int j = 0; j < 4; ++j) rmin[rt][j] = INFINITY;

  const f32x4 fz = {0.f, 0.f, 0.f, 0.f};

  // depth-2 register rotation; all indices literal at every call site
  bf16x8 bbuf[2][3];

  auto loadB = [&](int bi, int it) {   // bi literal at call sites
    const char* g = gW + (size_t)it * TILEB;
    #pragma unroll
    for (int ks = 0; ks < 3; ++ks)
      bbuf[bi][ks] = *(const bf16x8*)(g + ks * 1024);
  };

  auto compute = [&](int bi) {         // bi literal at call sites
    f32x4 acc[8];
    {
      bf16x8 bv = bbuf[bi][0];
      #pragma unroll
      for (int rt = 0; rt < 8; ++rt)
        acc[rt] = __builtin_amdgcn_mfma_f32_16x16x32_bf16(af[rt][0], bv, fz, 0, 0, 0);
    }
    #pragma unroll
    for (int ks = 1; ks < 3; ++ks) {
      bf16x8 bv = bbuf[bi][ks];
      #pragma unroll
      for (int rt = 0; rt < 8; ++rt)
        acc[rt] = __builtin_amdgcn_mfma_f32_16x16x32_bf16(af[rt][ks], bv, acc[rt], 0, 0, 0);
    }
    #pragma unroll
    for (int rt = 0; rt < 8; ++rt)
      #pragma unroll
      for (int j = 0; j < 4; ++j)
        rmin[rt][j] = fminf(rmin[rt][j], acc[rt][j]);
  };

  loadB(0, 0);
  loadB(1, 1);

  // main loop: compute(b)[k] then immediately re-issue load into buf b for
  // k+2 (WAR-safe: the load follows the consuming MFMAs in program order).
  int k = 0;
  #pragma unroll 1
  for (int tri = 0; tri < 27; ++tri, k += 2) {
    compute(0); loadB(0, k + 2);
    compute(1); loadB(1, k + 3);
  }
  // k == 54; computed 0..53; in flight: (0,54),(1,55)
  compute(0); loadB(0, 56);   // iter 54
  compute(1);                  // iter 55
  compute(0);                  // iter 56

  // min over the 16 key-cols (l15 lanes), then device atomicMin per row
  #pragma unroll
  for (int rt = 0; rt < 8; ++rt)
    #pragma unroll
    for (int j = 0; j < 4; ++j) {
      float m = rmin[rt][j];
      m = fminf(m, __shfl_xor(m, 1, 64));
      m = fminf(m, __shfl_xor(m, 2, 64));
      m = fminf(m, __shfl_xor(m, 4, 64));
      m = fminf(m, __shfl_xor(m, 8, 64));
      if (l15 == 0) {
        unsigned bu = __float_as_uint(m);
        unsigned tu = bu ^ (unsigned)(((int)bu >> 31) | (int)0x80000000);
        atomicMin(&rminb[brow + rt * 16 + l4 * 4 + j], tu);
      }
    }
}

// ------ final stage 1: decode + add qn, per-block partial sums ------------
__global__ __launch_bounds__(64) void final1_kernel(
    const unsigned* __restrict__ rminb, const float* __restrict__ qn,
    float* __restrict__ partial) {
  int r = blockIdx.x * 64 + threadIdx.x;   // grid 225 covers 14400 real rows
  unsigned u = rminb[r];
  unsigned bu = (u & 0x80000000u) ? (u ^ 0x80000000u) : ~u;
  float val = __uint_as_float(bu) + qn[r];
  #pragma unroll
  for (int off = 32; off; off >>= 1) val += __shfl_down(val, off, 64);
  if (threadIdx.x == 0) partial[blockIdx.x] = val;
}

// ------ final stage 2: deterministic sum of 225 partials ------------------
__global__ __launch_bounds__(256) void final2_kernel(
    const float* __restrict__ partial, float* __restrict__ out) {
  int t = threadIdx.x;
  float v = (t < 225) ? partial[t] : 0.f;
  #pragma unroll
  for (int off = 32; off; off >>= 1) v += __shfl_down(v, off, 64);
  __shared__ float s[4];
  if ((t & 63) == 0) s[t >> 6] = v;
  __syncthreads();
  if (t == 0) out[0] = s[0] + s[1] + s[2] + s[3];
}

extern "C" void kernel_launch(void* const* d_in, const int* in_sizes, int n_in,
                              void* d_out, int out_size, void* d_ws, size_t ws_size,
                              hipStream_t stream) {
  const float* resv = (const float*)d_in[0];
  const float* valv = (const float*)d_in[1];
  char* ws = (char*)d_ws;
  ushort_t* Qb      = (ushort_t*)ws;                 // 2,801,664 B (14592 rows)
  ushort_t* Kb      = (ushort_t*)(ws + 2801664);     // 2,801,664 B (14592 cols)
  float* qn         = (float*)(ws + 5603328);        //    58,368 B
  unsigned* rminb   = (unsigned*)(ws + 5661696);     //    58,368 B
  float* partial    = (float*)(ws + 5720064);        //       900 B
  float* out = (float*)d_out;

  prep_kernel<<<7296, 256, 0, stream>>>(resv, valv, Qb, Kb, qn, rminb);
  knn_kernel<<<456, 256, 0, stream>>>(Qb, Kb, rminb);
  final1_kernel<<<225, 64, 0, stream>>>(rminb, qn, partial);
  final2_kernel<<<1, 256, 0, stream>>>(partial, out);
}